// Round 7
// baseline (833.069 us; speedup 1.0000x reference)
//
#include <hip/hip_runtime.h>

#define N_NODES 50000
#define N_EDGES 800000
#define D 128            // D_IN == D_OUT == 128
#define NB 782           // row buckets of 64 rows: (50000+63)/64
#define CHUNK 4096       // edges per binscatter block

// Workspace layout (bytes):
#define S_OFF      0u            // S = X@W, bf16-packed uint[50000*64] = 12,800,000 B
#define GCNT_OFF   12800000u     // int[NB]   global bucket histogram
#define START_OFF  12803200u     // int[NB+1] bucket starts
#define GCUR_OFF   12806400u     // int[NB]   bucket fill cursors
#define RECS_OFF   12809600u     // uint2[800000] = 6,400,000 B
#define WS_NEEDED  (RECS_OFF + (size_t)N_EDGES * 8u)   // 19,209,600 B

__device__ __forceinline__ unsigned bf16_rne(float f) {
    unsigned u = __float_as_uint(f);
    return (u + 0x7fffu + ((u >> 16) & 1u)) >> 16;
}

// ---------------------------------------------------------------------------
// GEMM: S = X @ W, fp32 math, bf16 output (unchanged from round 6; 50 us,
// next round's target).
// ---------------------------------------------------------------------------
__global__ __launch_bounds__(512) void gc_gemm(const float* __restrict__ X,
                                               const float* __restrict__ W,
                                               unsigned* __restrict__ Sb) {
    __shared__ float4 LW[4096];
    const int t = threadIdx.x;
    const float4* W4 = (const float4*)W;
    #pragma unroll
    for (int i = 0; i < 8; ++i) LW[t + i * 512] = W4[t + i * 512];
    __syncthreads();

    const int rg = t >> 5;
    const int cg = t & 31;
    const int row0 = blockIdx.x * 64 + rg * 4;
    if (row0 >= N_NODES) return;

    const float4* x0 = (const float4*)(X + (size_t)(row0 + 0) * D);
    const float4* x1 = (const float4*)(X + (size_t)(row0 + 1) * D);
    const float4* x2 = (const float4*)(X + (size_t)(row0 + 2) * D);
    const float4* x3 = (const float4*)(X + (size_t)(row0 + 3) * D);

    float4 a0 = {0.f,0.f,0.f,0.f}, a1 = a0, a2 = a0, a3 = a0;

    #pragma unroll 4
    for (int k4 = 0; k4 < 32; ++k4) {
        float4 xv0 = x0[k4], xv1 = x1[k4], xv2 = x2[k4], xv3 = x3[k4];
        const float* xs0 = (const float*)&xv0;
        const float* xs1 = (const float*)&xv1;
        const float* xs2 = (const float*)&xv2;
        const float* xs3 = (const float*)&xv3;
        #pragma unroll
        for (int kk = 0; kk < 4; ++kk) {
            float4 wv = LW[(k4 * 4 + kk) * 32 + cg];
            float s0 = xs0[kk], s1 = xs1[kk], s2 = xs2[kk], s3 = xs3[kk];
            a0.x += s0 * wv.x; a0.y += s0 * wv.y; a0.z += s0 * wv.z; a0.w += s0 * wv.w;
            a1.x += s1 * wv.x; a1.y += s1 * wv.y; a1.z += s1 * wv.z; a1.w += s1 * wv.w;
            a2.x += s2 * wv.x; a2.y += s2 * wv.y; a2.z += s2 * wv.z; a2.w += s2 * wv.w;
            a3.x += s3 * wv.x; a3.y += s3 * wv.y; a3.z += s3 * wv.z; a3.w += s3 * wv.w;
        }
    }
    uint2* S2 = (uint2*)Sb;
    #define PACK2(f0, f1) (bf16_rne(f0) | (bf16_rne(f1) << 16))
    S2[(size_t)(row0 + 0) * 32 + cg] = make_uint2(PACK2(a0.x, a0.y), PACK2(a0.z, a0.w));
    S2[(size_t)(row0 + 1) * 32 + cg] = make_uint2(PACK2(a1.x, a1.y), PACK2(a1.z, a1.w));
    S2[(size_t)(row0 + 2) * 32 + cg] = make_uint2(PACK2(a2.x, a2.y), PACK2(a2.z, a2.w));
    S2[(size_t)(row0 + 3) * 32 + cg] = make_uint2(PACK2(a3.x, a3.y), PACK2(a3.z, a3.w));
    #undef PACK2
}

// ---------------------------------------------------------------------------
// Bucket histogram with LDS pre-aggregation.  gcnt pre-zeroed.
// ---------------------------------------------------------------------------
__global__ __launch_bounds__(256) void gc_bhist(const int* __restrict__ er,
                                                int* __restrict__ gcnt) {
    __shared__ int h[NB];
    const int t = threadIdx.x;
    for (int b = t; b < NB; b += 256) h[b] = 0;
    __syncthreads();
    for (int e = blockIdx.x * 256 + t; e < N_EDGES; e += gridDim.x * 256)
        atomicAdd(&h[er[e] >> 6], 1);
    __syncthreads();
    for (int b = t; b < NB; b += 256)
        if (h[b]) atomicAdd(&gcnt[b], h[b]);
}

// ---------------------------------------------------------------------------
// Single-block scan of NB bucket counts -> starts + cursors.
// ---------------------------------------------------------------------------
__global__ __launch_bounds__(256) void gc_bscan(const int* __restrict__ gcnt,
                                                int* __restrict__ start,
                                                int* __restrict__ gcursor) {
    __shared__ int sm[256];
    const int t = threadIdx.x;
    int c[4];
    int sum = 0;
    #pragma unroll
    for (int j = 0; j < 4; ++j) {
        int b = t * 4 + j;
        c[j] = (b < NB) ? gcnt[b] : 0;
        sum += c[j];
    }
    sm[t] = sum;
    __syncthreads();
    #pragma unroll
    for (int off = 1; off < 256; off <<= 1) {
        int v = (t >= off) ? sm[t - off] : 0;
        __syncthreads();
        sm[t] += v;
        __syncthreads();
    }
    int excl = sm[t] - sum;
    #pragma unroll
    for (int j = 0; j < 4; ++j) {
        int b = t * 4 + j;
        if (b < NB) { start[b] = excl; gcursor[b] = excl; }
        excl += c[j];
    }
    if (t == 0) start[NB] = N_EDGES;
}

// ---------------------------------------------------------------------------
// Bin-scatter: each block stages CHUNK edges in LDS grouped by bucket, then
// reserves one contiguous global chunk per bucket and writes run-wise.
// Record: x = (col<<16)|bf16(val), y = row.
// ---------------------------------------------------------------------------
__global__ __launch_bounds__(512) void gc_binscatter(const int* __restrict__ er,
                                                     const int* __restrict__ ec,
                                                     const float* __restrict__ ev,
                                                     int* __restrict__ gcursor,
                                                     uint2* __restrict__ recs) {
    __shared__ uint2 srec[CHUNK];     // 32 KB
    __shared__ int cnt[NB];
    __shared__ int base[NB];
    __shared__ int woff[NB];
    __shared__ int gbase[NB];
    __shared__ int sbuf[512];

    const int t = threadIdx.x;
    const int e0 = blockIdx.x * CHUNK;
    const int n = min(CHUNK, N_EDGES - e0);

    for (int b = t; b < NB; b += 512) cnt[b] = 0;
    __syncthreads();

    // phase 1: local bucket histogram
    for (int i = t; i < n; i += 512) atomicAdd(&cnt[er[e0 + i] >> 6], 1);
    __syncthreads();

    // phase 2: exclusive scan over NB (2 buckets/thread)
    int b0 = t * 2, b1 = t * 2 + 1;
    int c0 = (b0 < NB) ? cnt[b0] : 0;
    int c1 = (b1 < NB) ? cnt[b1] : 0;
    int s = c0 + c1;
    sbuf[t] = s;
    __syncthreads();
    #pragma unroll
    for (int off = 1; off < 512; off <<= 1) {
        int v = (t >= off) ? sbuf[t - off] : 0;
        __syncthreads();
        sbuf[t] += v;
        __syncthreads();
    }
    int excl = sbuf[t] - s;
    if (b0 < NB) { base[b0] = excl; woff[b0] = excl; }
    if (b1 < NB) { base[b1] = excl + c0; woff[b1] = excl + c0; }
    __syncthreads();

    // phase 3: stage records grouped by bucket
    for (int i = t; i < n; i += 512) {
        int r = er[e0 + i];
        int c = ec[e0 + i];
        float v = ev[e0 + i];
        int b = r >> 6;
        int pos = atomicAdd(&woff[b], 1);
        srec[pos] = make_uint2(((unsigned)c << 16) | bf16_rne(v), (unsigned)r);
    }
    __syncthreads();

    // phase 4: reserve global chunks
    for (int b = t; b < NB; b += 512)
        if (cnt[b]) gbase[b] = atomicAdd(&gcursor[b], cnt[b]);
    __syncthreads();

    // phase 5: run-wise copy to global bucket regions
    for (int i = t; i < n; i += 512) {
        uint2 rec = srec[i];
        int b = (int)(rec.y >> 6);
        recs[gbase[b] + (i - base[b])] = rec;
    }
}

// ---------------------------------------------------------------------------
// Fused gather: one block per bucket (64 rows), fp32 accumulator in LDS with
// permuted col layout c -> (c&1)*64 + (c>>1) so both ds_add streams hit 64
// consecutive words (2-way bank aliasing = free).
// ---------------------------------------------------------------------------
__global__ __launch_bounds__(256) void gc_gatherb(const unsigned* __restrict__ Sb,
                                                  const int* __restrict__ start,
                                                  const uint2* __restrict__ recs,
                                                  const float* __restrict__ bias,
                                                  float* __restrict__ out) {
    __shared__ float acc[64 * 128];   // 32 KB
    const int t = threadIdx.x;
    const int wv = t >> 6;
    const int lane = t & 63;
    const int b = blockIdx.x;

    for (int i = t; i < 64 * 128; i += 256) acc[i] = 0.f;
    __syncthreads();

    const int s = start[b];
    const int e = start[b + 1];

    int j = s + wv;
    for (; j + 4 < e; j += 8) {
        uint2 ra = recs[j];
        uint2 rb = recs[j + 4];
        unsigned sa = Sb[(size_t)(ra.x >> 16) * 64 + lane];
        unsigned sb = Sb[(size_t)(rb.x >> 16) * 64 + lane];
        float va = __uint_as_float(ra.x << 16);
        float vb = __uint_as_float(rb.x << 16);
        int rla = (int)(ra.y & 63) * 128;
        int rlb = (int)(rb.y & 63) * 128;
        atomicAdd(&acc[rla + lane],      va * __uint_as_float(sa << 16));
        atomicAdd(&acc[rla + 64 + lane], va * __uint_as_float(sa & 0xffff0000u));
        atomicAdd(&acc[rlb + lane],      vb * __uint_as_float(sb << 16));
        atomicAdd(&acc[rlb + 64 + lane], vb * __uint_as_float(sb & 0xffff0000u));
    }
    for (; j < e; j += 4) {
        uint2 ra = recs[j];
        unsigned sa = Sb[(size_t)(ra.x >> 16) * 64 + lane];
        float va = __uint_as_float(ra.x << 16);
        int rla = (int)(ra.y & 63) * 128;
        atomicAdd(&acc[rla + lane],      va * __uint_as_float(sa << 16));
        atomicAdd(&acc[rla + 64 + lane], va * __uint_as_float(sa & 0xffff0000u));
    }
    __syncthreads();

    // write out: wave wv handles rows wv*16..wv*16+15; lane covers cols 2l,2l+1
    float2 bv = ((const float2*)bias)[lane];
    #pragma unroll
    for (int k = 0; k < 16; ++k) {
        int rl = wv * 16 + k;
        int grow = b * 64 + rl;
        if (grow >= N_NODES) break;
        float2 o;
        o.x = acc[rl * 128 + lane] + bv.x;
        o.y = acc[rl * 128 + 64 + lane] + bv.y;
        ((float2*)(out + (size_t)grow * D))[lane] = o;
    }
}

// ---------------------------------------------------------------------------
extern "C" void kernel_launch(void* const* d_in, const int* in_sizes, int n_in,
                              void* d_out, int out_size, void* d_ws, size_t ws_size,
                              hipStream_t stream) {
    const float* X    = (const float*)d_in[0];
    const float* W    = (const float*)d_in[1];
    const float* bias = (const float*)d_in[2];
    const float* ev   = (const float*)d_in[3];
    const int*   er   = (const int*)  d_in[4];
    const int*   ec   = (const int*)  d_in[5];
    float* out = (float*)d_out;

    char* ws = (char*)d_ws;
    unsigned* Sb      = (unsigned*)(ws + S_OFF);
    int*      gcnt    = (int*)(ws + GCNT_OFF);
    int*      start   = (int*)(ws + START_OFF);
    int*      gcursor = (int*)(ws + GCUR_OFF);
    uint2*    recs    = (uint2*)(ws + RECS_OFF);

    // GEMM (bf16-packed output)
    gc_gemm<<<(N_NODES + 63) / 64, 512, 0, stream>>>(X, W, Sb);

    hipMemsetAsync(gcnt, 0, NB * sizeof(int), stream);

    gc_bhist<<<256, 256, 0, stream>>>(er, gcnt);
    gc_bscan<<<1, 256, 0, stream>>>(gcnt, start, gcursor);
    gc_binscatter<<<(N_EDGES + CHUNK - 1) / CHUNK, 512, 0, stream>>>(er, ec, ev, gcursor, recs);
    gc_gatherb<<<NB, 256, 0, stream>>>(Sb, start, recs, bias, out);
}

// Round 8
// 191.888 us; speedup vs baseline: 4.3414x; 4.3414x over previous
//
#include <hip/hip_runtime.h>

#define N_NODES 50000
#define N_EDGES 800000
#define D 128            // D_IN == D_OUT == 128
#define NB 782           // row buckets of 64 rows: (50000+63)/64
#define CHUNK 4096       // edges per binscatter block

// Workspace layout (bytes):
#define S_OFF      0u            // S = X@W, bf16-packed uint[50000*64] = 12,800,000 B
#define GCNT_OFF   12800000u     // int[NB]
#define START_OFF  12803200u     // int[NB+1]
#define GCUR_OFF   12806400u     // int[NB]
#define OFFS_OFF   12809600u     // int[N_NODES+1] = 200,004 B
#define RECS_OFF   13009664u     // uint2[800000] = 6,400,000 B
#define CSR_OFF    19409664u     // uint[800000]  = 3,200,000 B
#define WS_NEEDED  (CSR_OFF + (size_t)N_EDGES * 4u)   // 22,609,664 B

__device__ __forceinline__ unsigned bf16_rne(float f) {
    unsigned u = __float_as_uint(f);
    return (u + 0x7fffu + ((u >> 16) & 1u)) >> 16;
}

// ---------------------------------------------------------------------------
// GEMM: S = X @ W, fp32 math, bf16-packed output (proven, 50 us).
// ---------------------------------------------------------------------------
__global__ __launch_bounds__(512) void gc_gemm(const float* __restrict__ X,
                                               const float* __restrict__ W,
                                               unsigned* __restrict__ Sb) {
    __shared__ float4 LW[4096];
    const int t = threadIdx.x;
    const float4* W4 = (const float4*)W;
    #pragma unroll
    for (int i = 0; i < 8; ++i) LW[t + i * 512] = W4[t + i * 512];
    __syncthreads();

    const int rg = t >> 5;
    const int cg = t & 31;
    const int row0 = blockIdx.x * 64 + rg * 4;
    if (row0 >= N_NODES) return;

    const float4* x0 = (const float4*)(X + (size_t)(row0 + 0) * D);
    const float4* x1 = (const float4*)(X + (size_t)(row0 + 1) * D);
    const float4* x2 = (const float4*)(X + (size_t)(row0 + 2) * D);
    const float4* x3 = (const float4*)(X + (size_t)(row0 + 3) * D);

    float4 a0 = {0.f,0.f,0.f,0.f}, a1 = a0, a2 = a0, a3 = a0;

    #pragma unroll 4
    for (int k4 = 0; k4 < 32; ++k4) {
        float4 xv0 = x0[k4], xv1 = x1[k4], xv2 = x2[k4], xv3 = x3[k4];
        const float* xs0 = (const float*)&xv0;
        const float* xs1 = (const float*)&xv1;
        const float* xs2 = (const float*)&xv2;
        const float* xs3 = (const float*)&xv3;
        #pragma unroll
        for (int kk = 0; kk < 4; ++kk) {
            float4 wv = LW[(k4 * 4 + kk) * 32 + cg];
            float s0 = xs0[kk], s1 = xs1[kk], s2 = xs2[kk], s3 = xs3[kk];
            a0.x += s0 * wv.x; a0.y += s0 * wv.y; a0.z += s0 * wv.z; a0.w += s0 * wv.w;
            a1.x += s1 * wv.x; a1.y += s1 * wv.y; a1.z += s1 * wv.z; a1.w += s1 * wv.w;
            a2.x += s2 * wv.x; a2.y += s2 * wv.y; a2.z += s2 * wv.z; a2.w += s2 * wv.w;
            a3.x += s3 * wv.x; a3.y += s3 * wv.y; a3.z += s3 * wv.z; a3.w += s3 * wv.w;
        }
    }
    uint2* S2 = (uint2*)Sb;
    #define PACK2(f0, f1) (bf16_rne(f0) | (bf16_rne(f1) << 16))
    S2[(size_t)(row0 + 0) * 32 + cg] = make_uint2(PACK2(a0.x, a0.y), PACK2(a0.z, a0.w));
    S2[(size_t)(row0 + 1) * 32 + cg] = make_uint2(PACK2(a1.x, a1.y), PACK2(a1.z, a1.w));
    S2[(size_t)(row0 + 2) * 32 + cg] = make_uint2(PACK2(a2.x, a2.y), PACK2(a2.z, a2.w));
    S2[(size_t)(row0 + 3) * 32 + cg] = make_uint2(PACK2(a3.x, a3.y), PACK2(a3.z, a3.w));
    #undef PACK2
}

// ---------------------------------------------------------------------------
// Bucket histogram with LDS pre-aggregation.  gcnt pre-zeroed.
// ---------------------------------------------------------------------------
__global__ __launch_bounds__(256) void gc_bhist(const int* __restrict__ er,
                                                int* __restrict__ gcnt) {
    __shared__ int h[NB];
    const int t = threadIdx.x;
    for (int b = t; b < NB; b += 256) h[b] = 0;
    __syncthreads();
    for (int e = blockIdx.x * 256 + t; e < N_EDGES; e += gridDim.x * 256)
        atomicAdd(&h[er[e] >> 6], 1);
    __syncthreads();
    for (int b = t; b < NB; b += 256)
        if (h[b]) atomicAdd(&gcnt[b], h[b]);
}

// ---------------------------------------------------------------------------
// Single-block scan of NB bucket counts -> starts + cursors.
// ---------------------------------------------------------------------------
__global__ __launch_bounds__(256) void gc_bscan(const int* __restrict__ gcnt,
                                                int* __restrict__ start,
                                                int* __restrict__ gcursor) {
    __shared__ int sm[256];
    const int t = threadIdx.x;
    int c[4];
    int sum = 0;
    #pragma unroll
    for (int j = 0; j < 4; ++j) {
        int b = t * 4 + j;
        c[j] = (b < NB) ? gcnt[b] : 0;
        sum += c[j];
    }
    sm[t] = sum;
    __syncthreads();
    #pragma unroll
    for (int off = 1; off < 256; off <<= 1) {
        int v = (t >= off) ? sm[t - off] : 0;
        __syncthreads();
        sm[t] += v;
        __syncthreads();
    }
    int excl = sm[t] - sum;
    #pragma unroll
    for (int j = 0; j < 4; ++j) {
        int b = t * 4 + j;
        if (b < NB) { start[b] = excl; gcursor[b] = excl; }
        excl += c[j];
    }
    if (t == 0) start[NB] = N_EDGES;
}

// ---------------------------------------------------------------------------
// Bin-scatter (proven r7): stage CHUNK edges in LDS grouped by bucket, then
// reserve one contiguous global chunk per bucket and copy run-wise.
// Record: x = (col<<16)|bf16(val), y = row.
// ---------------------------------------------------------------------------
__global__ __launch_bounds__(512) void gc_binscatter(const int* __restrict__ er,
                                                     const int* __restrict__ ec,
                                                     const float* __restrict__ ev,
                                                     int* __restrict__ gcursor,
                                                     uint2* __restrict__ recs) {
    __shared__ uint2 srec[CHUNK];     // 32 KB
    __shared__ int cnt[NB];
    __shared__ int base[NB];
    __shared__ int woff[NB];
    __shared__ int gbase[NB];
    __shared__ int sbuf[512];

    const int t = threadIdx.x;
    const int e0 = blockIdx.x * CHUNK;
    const int n = min(CHUNK, N_EDGES - e0);

    for (int b = t; b < NB; b += 512) cnt[b] = 0;
    __syncthreads();

    for (int i = t; i < n; i += 512) atomicAdd(&cnt[er[e0 + i] >> 6], 1);
    __syncthreads();

    int b0 = t * 2, b1 = t * 2 + 1;
    int c0 = (b0 < NB) ? cnt[b0] : 0;
    int c1 = (b1 < NB) ? cnt[b1] : 0;
    int s = c0 + c1;
    sbuf[t] = s;
    __syncthreads();
    #pragma unroll
    for (int off = 1; off < 512; off <<= 1) {
        int v = (t >= off) ? sbuf[t - off] : 0;
        __syncthreads();
        sbuf[t] += v;
        __syncthreads();
    }
    int excl = sbuf[t] - s;
    if (b0 < NB) { base[b0] = excl; woff[b0] = excl; }
    if (b1 < NB) { base[b1] = excl + c0; woff[b1] = excl + c0; }
    __syncthreads();

    for (int i = t; i < n; i += 512) {
        int r = er[e0 + i];
        int c = ec[e0 + i];
        float v = ev[e0 + i];
        int b = r >> 6;
        int pos = atomicAdd(&woff[b], 1);
        srec[pos] = make_uint2(((unsigned)c << 16) | bf16_rne(v), (unsigned)r);
    }
    __syncthreads();

    for (int b = t; b < NB; b += 512)
        if (cnt[b]) gbase[b] = atomicAdd(&gcursor[b], cnt[b]);
    __syncthreads();

    for (int i = t; i < n; i += 512) {
        uint2 rec = srec[i];
        int b = (int)(rec.y >> 6);
        recs[gbase[b] + (i - base[b])] = rec;
    }
}

// ---------------------------------------------------------------------------
// Per-bucket counting sort: one block per bucket.  Sorts the bucket's records
// by row, emits packed uint CSR + per-row offsets.  All scattered writes land
// in the bucket's own ~4 KB CSR range (single CU -> full-line dirty, no
// cross-XCD bounce).
// ---------------------------------------------------------------------------
__global__ __launch_bounds__(256) void gc_bsort(const uint2* __restrict__ recs,
                                                const int* __restrict__ start,
                                                int* __restrict__ offsets,
                                                unsigned* __restrict__ csr) {
    __shared__ int h[64];
    __shared__ int cur[64];
    const int b = blockIdx.x;
    const int t = threadIdx.x;
    const int s = start[b];
    const int e = start[b + 1];

    if (t < 64) h[t] = 0;
    __syncthreads();

    for (int i = s + t; i < e; i += 256)
        atomicAdd(&h[recs[i].y & 63], 1);
    __syncthreads();

    if (t < 64) {
        int hv = h[t];
        int v = hv;
        #pragma unroll
        for (int off = 1; off < 64; off <<= 1) {
            int u = __shfl_up(v, off);
            if (t >= off) v += u;
        }
        int ex = s + v - hv;               // exclusive prefix + bucket start
        cur[t] = ex;
        int grow = b * 64 + t;
        if (grow < N_NODES) offsets[grow] = ex;
        if (grow == N_NODES - 1 || (b == NB - 1 && t == 63))
            offsets[N_NODES] = N_EDGES;
    }
    __syncthreads();

    for (int i = s + t; i < e; i += 256) {
        uint2 r = recs[i];
        int pos = atomicAdd(&cur[r.y & 63], 1);
        csr[pos] = r.x;
    }
}

// ---------------------------------------------------------------------------
// Gather (proven r6): one wave per row, lane owns 2 cols, register accum.
// ---------------------------------------------------------------------------
__global__ void gc_gather(const unsigned* __restrict__ Sb,
                          const int* __restrict__ offsets,
                          const unsigned* __restrict__ csr,
                          const float* __restrict__ bias,
                          float* __restrict__ out) {
    int wid  = (blockIdx.x * blockDim.x + threadIdx.x) >> 6;
    int lane = threadIdx.x & 63;
    if (wid >= N_NODES) return;

    int start = offsets[wid];
    int end   = offsets[wid + 1];

    float ax0 = 0.f, ay0 = 0.f, ax1 = 0.f, ay1 = 0.f;
    int e = start;
    for (; e + 3 < end; e += 4) {
        unsigned cv0 = csr[e];
        unsigned cv1 = csr[e + 1];
        unsigned cv2 = csr[e + 2];
        unsigned cv3 = csr[e + 3];
        unsigned s0 = Sb[(size_t)(cv0 >> 16) * 64 + lane];
        unsigned s1 = Sb[(size_t)(cv1 >> 16) * 64 + lane];
        unsigned s2 = Sb[(size_t)(cv2 >> 16) * 64 + lane];
        unsigned s3 = Sb[(size_t)(cv3 >> 16) * 64 + lane];
        float v0 = __uint_as_float(cv0 << 16);
        float v1 = __uint_as_float(cv1 << 16);
        float v2 = __uint_as_float(cv2 << 16);
        float v3 = __uint_as_float(cv3 << 16);
        ax0 += v0 * __uint_as_float(s0 << 16);
        ay0 += v0 * __uint_as_float(s0 & 0xffff0000u);
        ax1 += v1 * __uint_as_float(s1 << 16);
        ay1 += v1 * __uint_as_float(s1 & 0xffff0000u);
        ax0 += v2 * __uint_as_float(s2 << 16);
        ay0 += v2 * __uint_as_float(s2 & 0xffff0000u);
        ax1 += v3 * __uint_as_float(s3 << 16);
        ay1 += v3 * __uint_as_float(s3 & 0xffff0000u);
    }
    for (; e < end; ++e) {
        unsigned cv = csr[e];
        unsigned s = Sb[(size_t)(cv >> 16) * 64 + lane];
        float v = __uint_as_float(cv << 16);
        ax0 += v * __uint_as_float(s << 16);
        ay0 += v * __uint_as_float(s & 0xffff0000u);
    }

    float2 b = *(const float2*)(bias + lane * 2);
    float2 r = make_float2(ax0 + ax1 + b.x, ay0 + ay1 + b.y);
    *(float2*)(out + (size_t)wid * D + lane * 2) = r;
}

// ---------------------------------------------------------------------------
extern "C" void kernel_launch(void* const* d_in, const int* in_sizes, int n_in,
                              void* d_out, int out_size, void* d_ws, size_t ws_size,
                              hipStream_t stream) {
    const float* X    = (const float*)d_in[0];
    const float* W    = (const float*)d_in[1];
    const float* bias = (const float*)d_in[2];
    const float* ev   = (const float*)d_in[3];
    const int*   er   = (const int*)  d_in[4];
    const int*   ec   = (const int*)  d_in[5];
    float* out = (float*)d_out;

    char* ws = (char*)d_ws;
    unsigned* Sb      = (unsigned*)(ws + S_OFF);
    int*      gcnt    = (int*)(ws + GCNT_OFF);
    int*      start   = (int*)(ws + START_OFF);
    int*      gcursor = (int*)(ws + GCUR_OFF);
    int*      offsets = (int*)(ws + OFFS_OFF);
    uint2*    recs    = (uint2*)(ws + RECS_OFF);
    unsigned* csr     = (unsigned*)(ws + CSR_OFF);

    gc_gemm<<<(N_NODES + 63) / 64, 512, 0, stream>>>(X, W, Sb);

    hipMemsetAsync(gcnt, 0, NB * sizeof(int), stream);

    gc_bhist<<<256, 256, 0, stream>>>(er, gcnt);
    gc_bscan<<<1, 256, 0, stream>>>(gcnt, start, gcursor);
    gc_binscatter<<<(N_EDGES + CHUNK - 1) / CHUNK, 512, 0, stream>>>(er, ec, ev, gcursor, recs);
    gc_bsort<<<NB, 256, 0, stream>>>(recs, start, offsets, csr);

    int gblocks = (N_NODES * 64 + 255) / 256;
    gc_gather<<<gblocks, 256, 0, stream>>>(Sb, offsets, csr, bias, out);
}

// Round 11
// 169.004 us; speedup vs baseline: 4.9293x; 1.1354x over previous
//
#include <hip/hip_runtime.h>

#define N_NODES 50000
#define N_EDGES 800000
#define D 128            // D_IN == D_OUT == 128
#define NB 782           // row buckets of 64 rows: (50000+63)/64
#define CHUNK 4096       // edges per binscatter block

// Workspace layout (bytes):
#define S_OFF      0u            // S = X@W, bf16-packed uint[50000*64] = 12,800,000 B
#define GCNT_OFF   12800000u     // int[NB]
#define START_OFF  12803200u     // int[NB+1]
#define GCUR_OFF   12806400u     // int[NB]
#define OFFS_OFF   12809600u     // int[N_NODES+1] = 200,004 B
#define RECS_OFF   13009664u     // uint2[800000] = 6,400,000 B
#define CSR_OFF    19409664u     // uint[800000]  = 3,200,000 B
#define WS_NEEDED  (CSR_OFF + (size_t)N_EDGES * 4u)   // 22,609,664 B

typedef __attribute__((ext_vector_type(8))) short bf16x8;
typedef __attribute__((ext_vector_type(4))) float f32x4;

__device__ __forceinline__ unsigned bf16_rne(float f) {
    unsigned u = __float_as_uint(f);
    return (u + 0x7fffu + ((u >> 16) & 1u)) >> 16;
}

// ---------------------------------------------------------------------------
// MFMA GEMM v2 (de-risked): S = X @ W, bf16 inputs, fp32 accum, bf16 output.
// 256 threads = 4 waves; wave owns 16 rows.  W^T in LDS, PLAIN padded layout
// (stride 136 ushorts, no XOR).  D stored directly to global (no LDS
// epilogue) — the only cross-thread LDS dependency is stage W^T -> barrier ->
// read.  Fragment maps (verified m89):
//   A/B: lane l, elem e -> k = 4*(l>>4) + (e&3) + 16*(e>>2); row/col = l&15
//   D:   col = lane&15, row = 4*(lane>>4) + reg
// ---------------------------------------------------------------------------
__global__ __launch_bounds__(256) void gc_gemm_mfma(const float* __restrict__ X,
                                                    const float* __restrict__ W,
                                                    ushort* __restrict__ Sb16) {
    __shared__ unsigned lwtU[128 * 68];        // W^T bf16 pairs; row n at uint n*68
    const ushort* lwt = (const ushort*)lwtU;   // ushort view, row stride 136

    const int t = threadIdx.x;
    {
        const int n  = t >> 1;                 // 0..127
        const int kb = (t & 1) * 64;           // 0 or 64
        #pragma unroll
        for (int i = 0; i < 32; ++i) {
            int k = kb + 2 * i;
            unsigned lo = bf16_rne(W[(size_t)k * 128 + n]);
            unsigned hi = bf16_rne(W[(size_t)(k + 1) * 128 + n]);
            lwtU[n * 68 + (k >> 1)] = lo | (hi << 16);
        }
    }
    __syncthreads();

    const int wv   = t >> 6;
    const int lane = t & 63;
    const int g    = lane >> 4;                // 0..3
    const int lm   = lane & 15;
    const int row0 = blockIdx.x * 64 + wv * 16;
    if (row0 >= N_NODES) return;               // after the only barrier

    const int row = row0 + lm;
    const float4* xr = (const float4*)(X + (size_t)row * 128);

    f32x4 acc[8];
    #pragma unroll
    for (int i = 0; i < 8; ++i) acc[i] = (f32x4){0.f, 0.f, 0.f, 0.f};

    #pragma unroll
    for (int ks = 0; ks < 4; ++ks) {
        float4 x0 = xr[ks * 8 + g];            // k = ks*32 + 4g + j       (e0..3)
        float4 x1 = xr[ks * 8 + 4 + g];        // k = ks*32 + 16 + 4g + j  (e4..7)
        bf16x8 a;
        a[0] = (short)bf16_rne(x0.x); a[1] = (short)bf16_rne(x0.y);
        a[2] = (short)bf16_rne(x0.z); a[3] = (short)bf16_rne(x0.w);
        a[4] = (short)bf16_rne(x1.x); a[5] = (short)bf16_rne(x1.y);
        a[6] = (short)bf16_rne(x1.z); a[7] = (short)bf16_rne(x1.w);
        const int kk0 = ks * 32 + 4 * g;
        #pragma unroll
        for (int nt = 0; nt < 8; ++nt) {
            const int n = nt * 16 + lm;
            short4 b0 = *(const short4*)&lwt[n * 136 + kk0];        // 8B-aligned
            short4 b1 = *(const short4*)&lwt[n * 136 + kk0 + 16];
            bf16x8 b;
            b[0] = b0.x; b[1] = b0.y; b[2] = b0.z; b[3] = b0.w;
            b[4] = b1.x; b[5] = b1.y; b[6] = b1.z; b[7] = b1.w;
            acc[nt] = __builtin_amdgcn_mfma_f32_16x16x32_bf16(a, b, acc[nt], 0, 0, 0);
        }
    }

    // direct global store: D row = 4g+r, col = nt*16+lm; each (row,col) once
    #pragma unroll
    for (int r = 0; r < 4; ++r) {
        ushort* orow = Sb16 + (size_t)(row0 + 4 * g + r) * 128;
        #pragma unroll
        for (int nt = 0; nt < 8; ++nt)
            orow[nt * 16 + lm] = (ushort)bf16_rne(acc[nt][r]);
    }
}

// ---------------------------------------------------------------------------
// Bucket histogram with LDS pre-aggregation.  gcnt pre-zeroed.
// ---------------------------------------------------------------------------
__global__ __launch_bounds__(256) void gc_bhist(const int* __restrict__ er,
                                                int* __restrict__ gcnt) {
    __shared__ int h[NB];
    const int t = threadIdx.x;
    for (int b = t; b < NB; b += 256) h[b] = 0;
    __syncthreads();
    for (int e = blockIdx.x * 256 + t; e < N_EDGES; e += gridDim.x * 256)
        atomicAdd(&h[er[e] >> 6], 1);
    __syncthreads();
    for (int b = t; b < NB; b += 256)
        if (h[b]) atomicAdd(&gcnt[b], h[b]);
}

// ---------------------------------------------------------------------------
// Single-block scan of NB bucket counts -> starts + cursors.
// ---------------------------------------------------------------------------
__global__ __launch_bounds__(256) void gc_bscan(const int* __restrict__ gcnt,
                                                int* __restrict__ start,
                                                int* __restrict__ gcursor) {
    __shared__ int sm[256];
    const int t = threadIdx.x;
    int c[4];
    int sum = 0;
    #pragma unroll
    for (int j = 0; j < 4; ++j) {
        int b = t * 4 + j;
        c[j] = (b < NB) ? gcnt[b] : 0;
        sum += c[j];
    }
    sm[t] = sum;
    __syncthreads();
    #pragma unroll
    for (int off = 1; off < 256; off <<= 1) {
        int v = (t >= off) ? sm[t - off] : 0;
        __syncthreads();
        sm[t] += v;
        __syncthreads();
    }
    int excl = sm[t] - sum;
    #pragma unroll
    for (int j = 0; j < 4; ++j) {
        int b = t * 4 + j;
        if (b < NB) { start[b] = excl; gcursor[b] = excl; }
        excl += c[j];
    }
    if (t == 0) start[NB] = N_EDGES;
}

// ---------------------------------------------------------------------------
// Bin-scatter (proven r7/r8): stage CHUNK edges in LDS grouped by bucket,
// reserve one contiguous global chunk per bucket, copy run-wise.
// Record: x = (col<<16)|bf16(val), y = row.
// ---------------------------------------------------------------------------
__global__ __launch_bounds__(512) void gc_binscatter(const int* __restrict__ er,
                                                     const int* __restrict__ ec,
                                                     const float* __restrict__ ev,
                                                     int* __restrict__ gcursor,
                                                     uint2* __restrict__ recs) {
    __shared__ uint2 srec[CHUNK];     // 32 KB
    __shared__ int cnt[NB];
    __shared__ int base[NB];
    __shared__ int woff[NB];
    __shared__ int gbase[NB];
    __shared__ int sbuf[512];

    const int t = threadIdx.x;
    const int e0 = blockIdx.x * CHUNK;
    const int n = min(CHUNK, N_EDGES - e0);

    for (int b = t; b < NB; b += 512) cnt[b] = 0;
    __syncthreads();

    for (int i = t; i < n; i += 512) atomicAdd(&cnt[er[e0 + i] >> 6], 1);
    __syncthreads();

    int b0 = t * 2, b1 = t * 2 + 1;
    int c0 = (b0 < NB) ? cnt[b0] : 0;
    int c1 = (b1 < NB) ? cnt[b1] : 0;
    int s = c0 + c1;
    sbuf[t] = s;
    __syncthreads();
    #pragma unroll
    for (int off = 1; off < 512; off <<= 1) {
        int v = (t >= off) ? sbuf[t - off] : 0;
        __syncthreads();
        sbuf[t] += v;
        __syncthreads();
    }
    int excl = sbuf[t] - s;
    if (b0 < NB) { base[b0] = excl; woff[b0] = excl; }
    if (b1 < NB) { base[b1] = excl + c0; woff[b1] = excl + c0; }
    __syncthreads();

    for (int i = t; i < n; i += 512) {
        int r = er[e0 + i];
        int c = ec[e0 + i];
        float v = ev[e0 + i];
        int b = r >> 6;
        int pos = atomicAdd(&woff[b], 1);
        srec[pos] = make_uint2(((unsigned)c << 16) | bf16_rne(v), (unsigned)r);
    }
    __syncthreads();

    for (int b = t; b < NB; b += 512)
        if (cnt[b]) gbase[b] = atomicAdd(&gcursor[b], cnt[b]);
    __syncthreads();

    for (int i = t; i < n; i += 512) {
        uint2 rec = srec[i];
        int b = (int)(rec.y >> 6);
        recs[gbase[b] + (i - base[b])] = rec;
    }
}

// ---------------------------------------------------------------------------
// Per-bucket counting sort (proven r8): one block per bucket; emits packed
// uint CSR + per-row offsets, all writes inside the bucket's ~4 KB range.
// ---------------------------------------------------------------------------
__global__ __launch_bounds__(256) void gc_bsort(const uint2* __restrict__ recs,
                                                const int* __restrict__ start,
                                                int* __restrict__ offsets,
                                                unsigned* __restrict__ csr) {
    __shared__ int h[64];
    __shared__ int cur[64];
    const int b = blockIdx.x;
    const int t = threadIdx.x;
    const int s = start[b];
    const int e = start[b + 1];

    if (t < 64) h[t] = 0;
    __syncthreads();

    for (int i = s + t; i < e; i += 256)
        atomicAdd(&h[recs[i].y & 63], 1);
    __syncthreads();

    if (t < 64) {
        int hv = h[t];
        int v = hv;
        #pragma unroll
        for (int off = 1; off < 64; off <<= 1) {
            int u = __shfl_up(v, off);
            if (t >= off) v += u;
        }
        int ex = s + v - hv;
        cur[t] = ex;
        int grow = b * 64 + t;
        if (grow < N_NODES) offsets[grow] = ex;
        if (grow == N_NODES - 1 || (b == NB - 1 && t == 63))
            offsets[N_NODES] = N_EDGES;
    }
    __syncthreads();

    for (int i = s + t; i < e; i += 256) {
        uint2 r = recs[i];
        int pos = atomicAdd(&cur[r.y & 63], 1);
        csr[pos] = r.x;
    }
}

// ---------------------------------------------------------------------------
// Gather (proven r6/r8): one wave per row, lane owns 2 cols, register accum.
// ---------------------------------------------------------------------------
__global__ void gc_gather(const unsigned* __restrict__ Sb,
                          const int* __restrict__ offsets,
                          const unsigned* __restrict__ csr,
                          const float* __restrict__ bias,
                          float* __restrict__ out) {
    int wid  = (blockIdx.x * blockDim.x + threadIdx.x) >> 6;
    int lane = threadIdx.x & 63;
    if (wid >= N_NODES) return;

    int start = offsets[wid];
    int end   = offsets[wid + 1];

    float ax0 = 0.f, ay0 = 0.f, ax1 = 0.f, ay1 = 0.f;
    int e = start;
    for (; e + 3 < end; e += 4) {
        unsigned cv0 = csr[e];
        unsigned cv1 = csr[e + 1];
        unsigned cv2 = csr[e + 2];
        unsigned cv3 = csr[e + 3];
        unsigned s0 = Sb[(size_t)(cv0 >> 16) * 64 + lane];
        unsigned s1 = Sb[(size_t)(cv1 >> 16) * 64 + lane];
        unsigned s2 = Sb[(size_t)(cv2 >> 16) * 64 + lane];
        unsigned s3 = Sb[(size_t)(cv3 >> 16) * 64 + lane];
        float v0 = __uint_as_float(cv0 << 16);
        float v1 = __uint_as_float(cv1 << 16);
        float v2 = __uint_as_float(cv2 << 16);
        float v3 = __uint_as_float(cv3 << 16);
        ax0 += v0 * __uint_as_float(s0 << 16);
        ay0 += v0 * __uint_as_float(s0 & 0xffff0000u);
        ax1 += v1 * __uint_as_float(s1 << 16);
        ay1 += v1 * __uint_as_float(s1 & 0xffff0000u);
        ax0 += v2 * __uint_as_float(s2 << 16);
        ay0 += v2 * __uint_as_float(s2 & 0xffff0000u);
        ax1 += v3 * __uint_as_float(s3 << 16);
        ay1 += v3 * __uint_as_float(s3 & 0xffff0000u);
    }
    for (; e < end; ++e) {
        unsigned cv = csr[e];
        unsigned s = Sb[(size_t)(cv >> 16) * 64 + lane];
        float v = __uint_as_float(cv << 16);
        ax0 += v * __uint_as_float(s << 16);
        ay0 += v * __uint_as_float(s & 0xffff0000u);
    }

    float2 b = *(const float2*)(bias + lane * 2);
    float2 r = make_float2(ax0 + ax1 + b.x, ay0 + ay1 + b.y);
    *(float2*)(out + (size_t)wid * D + lane * 2) = r;
}

// ---------------------------------------------------------------------------
extern "C" void kernel_launch(void* const* d_in, const int* in_sizes, int n_in,
                              void* d_out, int out_size, void* d_ws, size_t ws_size,
                              hipStream_t stream) {
    const float* X    = (const float*)d_in[0];
    const float* W    = (const float*)d_in[1];
    const float* bias = (const float*)d_in[2];
    const float* ev   = (const float*)d_in[3];
    const int*   er   = (const int*)  d_in[4];
    const int*   ec   = (const int*)  d_in[5];
    float* out = (float*)d_out;

    char* ws = (char*)d_ws;
    ushort*   Sb16    = (ushort*)(ws + S_OFF);
    unsigned* Sb      = (unsigned*)(ws + S_OFF);
    int*      gcnt    = (int*)(ws + GCNT_OFF);
    int*      start   = (int*)(ws + START_OFF);
    int*      gcursor = (int*)(ws + GCUR_OFF);
    int*      offsets = (int*)(ws + OFFS_OFF);
    uint2*    recs    = (uint2*)(ws + RECS_OFF);
    unsigned* csr     = (unsigned*)(ws + CSR_OFF);

    gc_gemm_mfma<<<(N_NODES + 63) / 64, 256, 0, stream>>>(X, W, Sb16);

    hipMemsetAsync(gcnt, 0, NB * sizeof(int), stream);

    gc_bhist<<<256, 256, 0, stream>>>(er, gcnt);
    gc_bscan<<<1, 256, 0, stream>>>(gcnt, start, gcursor);
    gc_binscatter<<<(N_EDGES + CHUNK - 1) / CHUNK, 512, 0, stream>>>(er, ec, ev, gcursor, recs);
    gc_bsort<<<NB, 256, 0, stream>>>(recs, start, offsets, csr);

    int gblocks = (N_NODES * 64 + 255) / 256;
    gc_gather<<<gblocks, 256, 0, stream>>>(Sb, offsets, csr, bias, out);
}